// Round 14
// baseline (114.998 us; speedup 1.0000x reference)
//
#include <hip/hip_runtime.h>

typedef unsigned short u16;
typedef __attribute__((ext_vector_type(8))) short bf16x8;            // MFMA A/B frag
typedef __attribute__((ext_vector_type(8))) unsigned short u16x8;    // 8 bf16 = 16B
typedef __attribute__((ext_vector_type(4))) float f32x4;             // MFMA C/D frag

#define BLOCK 128        // 2 waves (k-halves); each block does 2 tiles, pipelined

__device__ __forceinline__ float bf2f(u16 u) {
    union { unsigned i; float f; } v; v.i = (unsigned)u << 16; return v.f;
}
__device__ __forceinline__ u16 f2bf(float f) {   // RNE f32 -> bf16
    union { float f; unsigned u; } v; v.f = f;
    unsigned r = v.u + 0x7fff + ((v.u >> 16) & 1);
    return (u16)(r >> 16);
}

// prep (R12 shape): feats f32 -> bf16 rows; kmat -> MFMA B-frag image
__global__ __launch_bounds__(256)
void prep_all(const float* __restrict__ feats, const float* __restrict__ kmat,
              u16* __restrict__ fbf, u16* __restrict__ kbg, int n8) {
    const int id = blockIdx.x * 256 + threadIdx.x;
    if (id < n8) {
        const float4 a = ((const float4*)feats)[2 * id];
        const float4 b = ((const float4*)feats)[2 * id + 1];
        union { u16 h[8]; int4 v; } p;
        p.h[0] = f2bf(a.x); p.h[1] = f2bf(a.y); p.h[2] = f2bf(a.z); p.h[3] = f2bf(a.w);
        p.h[4] = f2bf(b.x); p.h[5] = f2bf(b.y); p.h[6] = f2bf(b.z); p.h[7] = f2bf(b.w);
        ((int4*)fbf)[id] = p.v;
    }
    if (id < 16384) {
        const int k = id >> 6, n = id & 63;       // kmat flat = [k][n]
        const int kstep = k >> 5, quad = (k >> 3) & 3, j = k & 7;
        const int ntile = n >> 4, lanep = (quad << 4) | (n & 15);
        kbg[((((ntile << 3) | kstep) << 6) | lanep) * 8 + j] = f2bf(kmat[id]);
    }
}

// R14: grid-stride 2 tiles/block with A1 prefetch pipelining.
//   tile0: A1 -> bar -> [issue tile1 A1 loads] A2+B -> red bar -> store,
//          tile1 A1 math -> bar -> tile1 A2+B -> red bar -> store.
// Per-tile bodies identical to R12 (proven: no spill, conflict-free LDS).
template<bool WS>
__global__ __launch_bounds__(BLOCK)
void sphconv_pipe(const float* __restrict__ featsf,   // [N_IN, 64] f32
                  const u16* __restrict__ fbf,        // [N_IN, 64] bf16 (d_ws)
                  const u16* __restrict__ kbg,        // B-frag image (d_ws)
                  const float* __restrict__ in_pos,   // [N_IN, 3]
                  const float* __restrict__ out_pos,  // [N_OUT, 3]
                  const float* __restrict__ extents,  // [1]
                  const float* __restrict__ kmat,     // [4,64,64] = [k=256][f=64]
                  const float* __restrict__ bias,     // [64]
                  const int* __restrict__ nidx,       // [E]
                  const int* __restrict__ rsplits,    // [N_OUT+1]
                  float* __restrict__ out,            // [N_OUT,64]
                  int n_out, int ntiles, int n_edges)
{
    __shared__ _Float16 sphT[16][16][4];               // [t][m][s]   2 KB
    __shared__ int      idxT[16][16];                  // [t][m]      1 KB
    __shared__ __align__(16) float redT[4][64][4];     // [nt][lane]  4 KB

    const int tid  = threadIdx.x;
    const int kh   = tid >> 6;                // wave = k-half (c-half)
    const int lane = tid & 63;
    const int m = lane & 15, quad = lane >> 4;
    const float inv_ext = __fdividef(1.f, extents[0]);

    const int t0 = blockIdx.x * 2;
    const int t1 = t0 + 1;

    // A1 prefetch state (registers; ~15 VGPRs)
    int   a_id[2]; bool a_v[2];
    float a_px[2], a_py[2], a_pz[2], a_qx[2], a_qy[2], a_qz[2];

    auto a1_issue = [&](int tile) {
        const int obase = min(tile, ntiles - 1) << 4;
        #pragma unroll
        for (int u = 0; u < 2; ++u) {
            const int slot = (u << 7) | tid;          // 0..255, lane-contiguous
            const int mm = slot >> 4, t = slot & 15;
            const int o  = obase + mm;
            const int oc = min(o, n_out - 1);
            const int e0 = rsplits[oc], e1 = rsplits[oc + 1];
            const int e  = e0 + t;
            a_v[u] = (o < n_out) && (e < e1);
            const int id = nidx[min(e, n_edges - 1)]; // coalesced (e ~ slot)
            a_id[u] = id;
            a_px[u] = in_pos[id * 3 + 0];
            a_py[u] = in_pos[id * 3 + 1];
            a_pz[u] = in_pos[id * 3 + 2];
            a_qx[u] = out_pos[oc * 3 + 0];
            a_qy[u] = out_pos[oc * 3 + 1];
            a_qz[u] = out_pos[oc * 3 + 2];
        }
    };

    auto a1_math = [&]() {
        #pragma unroll
        for (int u = 0; u < 2; ++u) {
            const int slot = (u << 7) | tid;
            const int mm = slot >> 4, t = slot & 15;
            const float dx = a_px[u] - a_qx[u];
            const float dy = a_py[u] - a_qy[u];
            const float dz = a_pz[u] - a_qz[u];
            const float rp2 = dx * dx + dy * dy;
            const float r2  = rp2 + dz * dz;
            const float rs  = fmaxf(sqrtf(r2), 1e-10f);
            const float rp  = fmaxf(sqrtf(rp2), 1e-10f);
            const float ir  = __fdividef(1.f, rs);
            const float irp = __fdividef(1.f, rp);
            union { _Float16 hh[4]; short4 s4; } pk;
            pk.hh[0] = (_Float16)(a_v[u] ? rs * inv_ext : 0.f);
            pk.hh[1] = (_Float16)(a_v[u] ? dz * ir      : 0.f);
            pk.hh[2] = (_Float16)(a_v[u] ? dy * irp     : 0.f);
            pk.hh[3] = (_Float16)(a_v[u] ? dx * irp     : 0.f);
            idxT[t][mm] = a_id[u];                    // [t][m]: A2 conflict-free
            *(short4*)&sphT[t][mm][0] = pk.s4;
        }
    };

    auto compute = [&](f32x4* C) {   // A2 + B for the tile staged in sphT/idxT
        float acc[4][8];
        #pragma unroll
        for (int s = 0; s < 4; ++s)
            #pragma unroll
            for (int j = 0; j < 8; ++j) acc[s][j] = 0.f;

        #pragma unroll 4
        for (int t = 0; t < 16; ++t) {
            const int idx = idxT[t][m];               // broadcast across quads
            union { short4 s4; _Float16 hh[4]; } up;
            up.s4 = *(const short4*)&sphT[t][m][0];
            float fv[8];
            if constexpr (WS) {
                const u16x8 f0 = *(const u16x8*)(fbf + (idx << 6) + (kh << 5) + (quad << 3));
                #pragma unroll
                for (int j = 0; j < 8; ++j) fv[j] = bf2f(f0[j]);
            } else {
                const float* fr = featsf + (idx << 6) + (kh << 5) + (quad << 3);
                const float4 a0 = *(const float4*)fr;
                const float4 a1 = *(const float4*)(fr + 4);
                fv[0] = a0.x; fv[1] = a0.y; fv[2] = a0.z; fv[3] = a0.w;
                fv[4] = a1.x; fv[5] = a1.y; fv[6] = a1.z; fv[7] = a1.w;
            }
            #pragma unroll
            for (int s = 0; s < 4; ++s) {
                const float w = (float)up.hh[s];
                #pragma unroll
                for (int j = 0; j < 8; ++j)
                    acc[s][j] = fmaf(w, fv[j], acc[s][j]);
            }
        }

        bf16x8 afr[4];
        #pragma unroll
        for (int s = 0; s < 4; ++s) {
            union { u16 hh[8]; bf16x8 v; } p;
            #pragma unroll
            for (int j = 0; j < 8; ++j) p.hh[j] = f2bf(acc[s][j]);
            afr[s] = p.v;
        }

        #pragma unroll
        for (int nt = 0; nt < 4; ++nt) {
            C[nt] = (f32x4){0.f, 0.f, 0.f, 0.f};
            bf16x8 b[4];
            #pragma unroll
            for (int s = 0; s < 4; ++s) {
                const int ks = (s << 1) | kh;
                if constexpr (WS) {
                    b[s] = *(const bf16x8*)(kbg + ((((nt << 3) | ks) << 6) | lane) * 8);
                } else {
                    union { u16 hh[8]; bf16x8 v; } p;
                    #pragma unroll
                    for (int j = 0; j < 8; ++j) {
                        const int k = (ks << 5) | (quad << 3) | j;
                        const int n = (nt << 4) | m;
                        p.hh[j] = f2bf(kmat[k * 64 + n]);
                    }
                    b[s] = p.v;
                }
            }
            #pragma unroll
            for (int s = 0; s < 4; ++s)
                C[nt] = __builtin_amdgcn_mfma_f32_16x16x32_bf16(afr[s], b[s], C[nt], 0, 0, 0);
        }
    };

    auto reduce_store = [&](const f32x4* C, int tile) {
        if (kh == 1) {
            #pragma unroll
            for (int nt = 0; nt < 4; ++nt)
                *(f32x4*)&redT[nt][lane][0] = C[nt];  // ds_write_b128, dense
        }
        __syncthreads();                               // red ready / prior LDS reads done
        if (kh == 0 && tile < ntiles) {
            const int obase = tile << 4;
            #pragma unroll
            for (int nt = 0; nt < 4; ++nt) {
                const f32x4 P = *(const f32x4*)&redT[nt][lane][0];
                const int f = (nt << 4) | m;          // D: n = lane&15
                const float bv = bias[f];
                #pragma unroll
                for (int r = 0; r < 4; ++r) {
                    const int oo = obase + (quad << 2) + r;   // D: m = quad*4 + r
                    if (oo < n_out) out[(oo << 6) | f] = C[nt][r] + P[r] + bv;
                }
            }
        }
    };

    // ---------------- pipeline ----------------
    a1_issue(t0);
    a1_math();
    __syncthreads();                 // (1) tile0 sph/idx staged

    a1_issue(t1);                    // prefetch tile1's A1 loads under tile0 compute
    f32x4 C0[4];
    compute(C0);                     // tile0 A2 + B
    reduce_store(C0, t0);            // contains barrier (2): red + A2-read drain
    a1_math();                       // tile1 sph/idx -> LDS (loads already arrived)
    __syncthreads();                 // (3) tile1 staged; tile0 red reads done

    f32x4 C1[4];
    compute(C1);                     // tile1 A2 + B
    reduce_store(C1, t1);            // barrier (4) + store
}

extern "C" void kernel_launch(void* const* d_in, const int* in_sizes, int n_in,
                              void* d_out, int out_size, void* d_ws, size_t ws_size,
                              hipStream_t stream) {
    const float* feats   = (const float*)d_in[0];
    const float* in_pos  = (const float*)d_in[1];
    const float* out_pos = (const float*)d_in[2];
    const float* extents = (const float*)d_in[3];
    const float* kmat    = (const float*)d_in[4];
    const float* bias    = (const float*)d_in[5];
    const int*   nidx    = (const int*)d_in[6];
    const int*   rsplits = (const int*)d_in[7];
    const int n_out   = in_sizes[7] - 1;
    const int n_edges = in_sizes[6];
    const int ntiles  = (n_out + 15) >> 4;
    const int grid    = (ntiles + 1) >> 1;     // 2 tiles per block

    const size_t fbf_bytes = (size_t)in_sizes[0] * 2;
    const size_t need = fbf_bytes + 32768;
    if (ws_size >= need && (in_sizes[0] & 7) == 0) {
        u16* fbf = (u16*)d_ws;
        u16* kbg = (u16*)((char*)d_ws + fbf_bytes);
        const int n8 = in_sizes[0] / 8;
        const int pmax = n8 > 16384 ? n8 : 16384;
        prep_all<<<(pmax + 255) / 256, 256, 0, stream>>>(feats, kmat, fbf, kbg, n8);
        sphconv_pipe<true><<<grid, BLOCK, 0, stream>>>(
            feats, fbf, kbg, in_pos, out_pos, extents, kmat, bias, nidx, rsplits,
            (float*)d_out, n_out, ntiles, n_edges);
    } else {
        sphconv_pipe<false><<<grid, BLOCK, 0, stream>>>(
            feats, nullptr, nullptr, in_pos, out_pos, extents, kmat, bias, nidx, rsplits,
            (float*)d_out, n_out, ntiles, n_edges);
    }
}

// Round 15
// 106.944 us; speedup vs baseline: 1.0753x; 1.0753x over previous
//
#include <hip/hip_runtime.h>

typedef unsigned short u16;
typedef unsigned int u32;
typedef __attribute__((ext_vector_type(8))) short bf16x8;            // MFMA A/B frag
typedef __attribute__((ext_vector_type(2))) float v2f;               // packed f32 pair
typedef __attribute__((ext_vector_type(4))) float f32x4;             // MFMA C/D frag

#define BLOCK 128        // one tile (16 outputs) per block; 2 k-half waves

__device__ __forceinline__ float bf2f(u16 u) {
    union { unsigned i; float f; } v; v.i = (unsigned)u << 16; return v.f;
}
__device__ __forceinline__ float asf(u32 u) {
    union { u32 i; float f; } v; v.i = u; return v.f;
}
__device__ __forceinline__ u16 f2bf(float f) {   // RNE f32 -> bf16
    union { float f; unsigned u; } v; v.f = f;
    unsigned r = v.u + 0x7fff + ((v.u >> 16) & 1);
    return (u16)(r >> 16);
}

// prep: (a) feats f32 -> bf16 rows (R8: halves gather traffic);
//       (b) kmat -> ready-made MFMA B-fragment image (R11)
__global__ __launch_bounds__(256)
void prep_all(const float* __restrict__ feats, const float* __restrict__ kmat,
              u16* __restrict__ fbf, u16* __restrict__ kbg, int n8) {
    const int id = blockIdx.x * 256 + threadIdx.x;
    if (id < n8) {
        const float4 a = ((const float4*)feats)[2 * id];
        const float4 b = ((const float4*)feats)[2 * id + 1];
        union { u16 h[8]; int4 v; } p;
        p.h[0] = f2bf(a.x); p.h[1] = f2bf(a.y); p.h[2] = f2bf(a.z); p.h[3] = f2bf(a.w);
        p.h[4] = f2bf(b.x); p.h[5] = f2bf(b.y); p.h[6] = f2bf(b.z); p.h[7] = f2bf(b.w);
        ((int4*)fbf)[id] = p.v;
    }
    if (id < 16384) {
        const int k = id >> 6, n = id & 63;       // kmat flat = [k][n]
        const int kstep = k >> 5, quad = (k >> 3) & 3, j = k & 7;
        const int ntile = n >> 4, lanep = (quad << 4) | (n & 15);
        kbg[((((ntile << 3) | kstep) << 6) | lanep) * 8 + j] = f2bf(kmat[id]);
    }
}

// R15 = R12 (best: 107.5 us) + packed-f32 A2 accumulation (v_pk_fma_f32).
//   A1: 256 (m,t) slots over 128 threads -> f16 sph + idx in LDS [t][m]
//   A2: lane(m=lane&15,quad) acc2[s][p] += sph_t[s]*featpair[idx_t], pk-fma
//   B : 4 nt x 4 ks mfma_f32_16x16x32_bf16; B-frags from global kbg image
//   Red: kh=1 writes C (4 KB LDS); kh=0 sums + bias + stores. 2 barriers.
template<bool WS>
__global__ __launch_bounds__(BLOCK)
void sphconv_tile(const float* __restrict__ featsf,   // [N_IN, 64] f32
                  const u16* __restrict__ fbf,        // [N_IN, 64] bf16 (d_ws)
                  const u16* __restrict__ kbg,        // B-frag image (d_ws)
                  const float* __restrict__ in_pos,   // [N_IN, 3]
                  const float* __restrict__ out_pos,  // [N_OUT, 3]
                  const float* __restrict__ extents,  // [1]
                  const float* __restrict__ kmat,     // [4,64,64] = [k=256][f=64]
                  const float* __restrict__ bias,     // [64]
                  const int* __restrict__ nidx,       // [E]
                  const int* __restrict__ rsplits,    // [N_OUT+1]
                  float* __restrict__ out,            // [N_OUT,64]
                  int n_out, int n_edges)
{
    __shared__ _Float16 sphT[16][16][4];               // [t][m][s]   2 KB
    __shared__ int      idxT[16][16];                  // [t][m]      1 KB
    __shared__ __align__(16) float redT[4][64][4];     // [nt][lane]  4 KB

    const int tid = threadIdx.x;
    const int kh  = tid >> 6;                 // wave = k-half (c-half)
    const int lane = tid & 63;
    const int m = lane & 15, quad = lane >> 4;
    const int obase = blockIdx.x << 4;

    const float inv_ext = __fdividef(1.f, extents[0]);

    // ---- A1: tile's 256 (m,t) slots over 128 threads, 2 per thread ----
    #pragma unroll
    for (int u = 0; u < 2; ++u) {
        const int slot = (u << 7) | tid;      // 0..255, lane-contiguous
        const int mm = slot >> 4, t = slot & 15;
        const int o  = obase + mm;
        const int oc = min(o, n_out - 1);
        const int e0 = rsplits[oc], e1 = rsplits[oc + 1];
        const int e  = e0 + t;
        const bool v = (o < n_out) && (e < e1);
        const int id = nidx[min(e, n_edges - 1)];     // coalesced (e ~ slot)
        const float dx = in_pos[id * 3 + 0] - out_pos[oc * 3 + 0];
        const float dy = in_pos[id * 3 + 1] - out_pos[oc * 3 + 1];
        const float dz = in_pos[id * 3 + 2] - out_pos[oc * 3 + 2];
        const float rp2 = dx * dx + dy * dy;
        const float r2  = rp2 + dz * dz;
        const float rs  = fmaxf(sqrtf(r2), 1e-10f);
        const float rp  = fmaxf(sqrtf(rp2), 1e-10f);
        const float ir  = __fdividef(1.f, rs);
        const float irp = __fdividef(1.f, rp);
        union { _Float16 hh[4]; short4 s4; } pk;
        pk.hh[0] = (_Float16)(v ? rs * inv_ext : 0.f);
        pk.hh[1] = (_Float16)(v ? dz * ir      : 0.f);
        pk.hh[2] = (_Float16)(v ? dy * irp     : 0.f);
        pk.hh[3] = (_Float16)(v ? dx * irp     : 0.f);
        idxT[t][mm] = id;                             // [t][m]: A2 conflict-free
        *(short4*)&sphT[t][mm][0] = pk.s4;
    }
    __syncthreads();

    // ---- A2: packed-f32 accumulation (pairs p: elements 2p, 2p+1) ----
    v2f acc2[4][4];
    #pragma unroll
    for (int s = 0; s < 4; ++s)
        #pragma unroll
        for (int p = 0; p < 4; ++p) acc2[s][p] = (v2f){0.f, 0.f};

    #pragma unroll 4
    for (int t = 0; t < 16; ++t) {
        const int idx = idxT[t][m];                   // broadcast across quads
        union { short4 s4; _Float16 hh[4]; } up;
        up.s4 = *(const short4*)&sphT[t][m][0];
        v2f fv[4];
        if constexpr (WS) {
            const uint4 w4 = *(const uint4*)(fbf + (idx << 6) + (kh << 5) + (quad << 3));
            const u32 wv[4] = {w4.x, w4.y, w4.z, w4.w};
            #pragma unroll
            for (int p = 0; p < 4; ++p)
                fv[p] = (v2f){asf(wv[p] << 16), asf(wv[p] & 0xffff0000u)};
        } else {
            const float* fr = featsf + (idx << 6) + (kh << 5) + (quad << 3);
            const float4 a0 = *(const float4*)fr;
            const float4 a1 = *(const float4*)(fr + 4);
            fv[0] = (v2f){a0.x, a0.y}; fv[1] = (v2f){a0.z, a0.w};
            fv[2] = (v2f){a1.x, a1.y}; fv[3] = (v2f){a1.z, a1.w};
        }
        #pragma unroll
        for (int s = 0; s < 4; ++s) {
            const float w = (float)up.hh[s];
            const v2f ws = (v2f){w, w};
            #pragma unroll
            for (int p = 0; p < 4; ++p)
                acc2[s][p] = fv[p] * ws + acc2[s][p];   // v_pk_fma_f32
        }
    }

    // ---- pack -> bf16 A-frags (element j = 2p + (j&1)) ----
    bf16x8 afr[4];
    #pragma unroll
    for (int s = 0; s < 4; ++s) {
        union { u16 hh[8]; bf16x8 v; } p;
        #pragma unroll
        for (int pp = 0; pp < 4; ++pp) {
            p.hh[2 * pp]     = f2bf(acc2[s][pp].x);
            p.hh[2 * pp + 1] = f2bf(acc2[s][pp].y);
        }
        afr[s] = p.v;
    }

    // ---- B: 4 nt x 4 ks MFMA; B-frags from global (coalesced 1 KB loads) ----
    f32x4 C[4] = {{0,0,0,0},{0,0,0,0},{0,0,0,0},{0,0,0,0}};
    #pragma unroll
    for (int nt = 0; nt < 4; ++nt) {
        bf16x8 b[4];
        #pragma unroll
        for (int s = 0; s < 4; ++s) {
            const int ks = (s << 1) | kh;
            if constexpr (WS) {
                b[s] = *(const bf16x8*)(kbg + ((((nt << 3) | ks) << 6) | lane) * 8);
            } else {
                union { u16 hh[8]; bf16x8 v; } p;
                #pragma unroll
                for (int j = 0; j < 8; ++j) {
                    const int k = (ks << 5) | (quad << 3) | j;
                    const int n = (nt << 4) | m;
                    p.hh[j] = f2bf(kmat[k * 64 + n]);
                }
                b[s] = p.v;
            }
        }
        #pragma unroll
        for (int s = 0; s < 4; ++s)
            C[nt] = __builtin_amdgcn_mfma_f32_16x16x32_bf16(afr[s], b[s], C[nt], 0, 0, 0);
    }

    // ---- pair reduction + epilogue ----
    if (kh == 1) {
        #pragma unroll
        for (int nt = 0; nt < 4; ++nt)
            *(f32x4*)&redT[nt][lane][0] = C[nt];      // ds_write_b128, dense
    }
    __syncthreads();
    if (kh == 0) {
        #pragma unroll
        for (int nt = 0; nt < 4; ++nt) {
            const f32x4 P = *(const f32x4*)&redT[nt][lane][0];
            const int f = (nt << 4) | m;              // D: n = lane&15
            const float bv = bias[f];
            #pragma unroll
            for (int r = 0; r < 4; ++r) {
                const int oo = obase + (quad << 2) + r;   // D: m = quad*4 + r
                if (oo < n_out) out[(oo << 6) | f] = C[nt][r] + P[r] + bv;
            }
        }
    }
}

extern "C" void kernel_launch(void* const* d_in, const int* in_sizes, int n_in,
                              void* d_out, int out_size, void* d_ws, size_t ws_size,
                              hipStream_t stream) {
    const float* feats   = (const float*)d_in[0];
    const float* in_pos  = (const float*)d_in[1];
    const float* out_pos = (const float*)d_in[2];
    const float* extents = (const float*)d_in[3];
    const float* kmat    = (const float*)d_in[4];
    const float* bias    = (const float*)d_in[5];
    const int*   nidx    = (const int*)d_in[6];
    const int*   rsplits = (const int*)d_in[7];
    const int n_out   = in_sizes[7] - 1;
    const int n_edges = in_sizes[6];
    const int ntiles  = (n_out + 15) >> 4;

    const size_t fbf_bytes = (size_t)in_sizes[0] * 2;
    const size_t need = fbf_bytes + 32768;
    if (ws_size >= need && (in_sizes[0] & 7) == 0) {
        u16* fbf = (u16*)d_ws;
        u16* kbg = (u16*)((char*)d_ws + fbf_bytes);
        const int n8 = in_sizes[0] / 8;
        const int pmax = n8 > 16384 ? n8 : 16384;
        prep_all<<<(pmax + 255) / 256, 256, 0, stream>>>(feats, kmat, fbf, kbg, n8);
        sphconv_tile<true><<<ntiles, BLOCK, 0, stream>>>(
            feats, fbf, kbg, in_pos, out_pos, extents, kmat, bias, nidx, rsplits,
            (float*)d_out, n_out, n_edges);
    } else {
        sphconv_tile<false><<<ntiles, BLOCK, 0, stream>>>(
            feats, nullptr, nullptr, in_pos, out_pos, extents, kmat, bias, nidx, rsplits,
            (float*)d_out, n_out, n_edges);
    }
}